// Round 8
// baseline (996.876 us; speedup 1.0000x reference)
//
#include <hip/hip_runtime.h>
#include <hip/hip_bf16.h>
#include <cstdint>

// MMoE: B=16384, F=1024, E=8, U=512, EH=1024/1024, TH=512/256, T=4
#define B_ 16384
#define F_ 1024
#define E_ 8
#define U_ 512
#define EH1_ 1024
#define EH2_ 1024
#define TH1_ 512
#define TH2_ 256
#define T_ 4

typedef __attribute__((ext_vector_type(4))) float f32x4;
typedef __attribute__((ext_vector_type(8))) short bf16x8;
typedef __attribute__((ext_vector_type(4))) short s16x4;

__device__ __forceinline__ short f2bf(float f) {
  union { float f; unsigned u; } v; v.f = f;
  unsigned r = v.u + 0x7fffu + ((v.u >> 16) & 1u);  // RNE
  return (short)(r >> 16);
}
__device__ __forceinline__ float bf2f(short s) {
  union { unsigned u; float f; } v; v.u = ((unsigned)(unsigned short)s) << 16;
  return v.f;
}

__device__ __forceinline__ void gload16(const void* g, void* l) {
  __builtin_amdgcn_global_load_lds(
      (const __attribute__((address_space(1))) void*)g,
      (__attribute__((address_space(3))) void*)l, 16, 0, 0);
}

// ---- fp32 -> (bf16 main, bf16 residual) elementwise, 8/thread ----
__global__ __launch_bounds__(256) void conv_dual(const float* __restrict__ in,
                                                 short* __restrict__ ob,
                                                 short* __restrict__ orr, long n) {
  long i = ((long)blockIdx.x * 256 + threadIdx.x) * 8;
  if (i >= n) return;
  const float4* p = (const float4*)(in + i);
  float4 a = p[0], b = p[1];
  float v[8] = {a.x, a.y, a.z, a.w, b.x, b.y, b.z, b.w};
  bf16x8 o, r;
#pragma unroll
  for (int j = 0; j < 8; j++) {
    short s = f2bf(v[j]);
    o[j] = s;
    r[j] = f2bf(v[j] - bf2f(s));
  }
  *(bf16x8*)(ob + i) = o;
  *(bf16x8*)(orr + i) = r;
}

// ---- fp32 [Z][K][N] -> bf16 [Z][N][K] (transpose-convert) ----
__global__ __launch_bounds__(256) void trans_conv(const float* __restrict__ W,
                                                  short* __restrict__ Wt, int K, int N) {
  __shared__ float tile[32][33];
  const int e = blockIdx.z;
  const int k0 = blockIdx.x * 32, n0 = blockIdx.y * 32;
  const float* We = W + (size_t)e * K * N;
  short* Wte = Wt + (size_t)e * N * K;
  const int tx = threadIdx.x, ty = threadIdx.y;  // block (32,8)
#pragma unroll
  for (int r = 0; r < 32; r += 8)
    tile[ty + r][tx] = We[(size_t)(k0 + ty + r) * N + (n0 + tx)];
  __syncthreads();
#pragma unroll
  for (int r = 0; r < 32; r += 8)
    Wte[(size_t)(n0 + ty + r) * K + (k0 + tx)] = f2bf(tile[tx][ty + r]);
}

// ---- Wg[T][F][E] fp32 -> pair-major bf16 Wp[32][F] + residual Wr[32][F] ----
__global__ __launch_bounds__(256) void trans_wg(const float* __restrict__ Wg,
                                                short* __restrict__ Wp,
                                                short* __restrict__ Wr) {
  int idx = blockIdx.x * 256 + threadIdx.x;  // 32*1024
  int p = idx >> 10, f = idx & 1023;
  int t = p >> 3, e = p & 7;
  float w = Wg[((size_t)t * F_ + f) * E_ + e];
  short wb = f2bf(w);
  Wp[idx] = wb;
  Wr[idx] = f2bf(w - bf2f(wb));
}

// ---- gate logits via 3-term bf16 MFMA + fused softmax over E ----
__global__ __launch_bounds__(256) void glogits(const short* __restrict__ xb,
                                               const short* __restrict__ xr,
                                               const short* __restrict__ Wp,
                                               const short* __restrict__ Wr,
                                               float* __restrict__ gates) {
  const int wid = threadIdx.x >> 6, lane = threadIdx.x & 63;
  const int m0 = blockIdx.x * 64 + wid * 16;
  const int fr = lane & 15, kg = (lane >> 4) * 8;
  f32x4 acc[2];
#pragma unroll
  for (int j = 0; j < 2; j++)
#pragma unroll
    for (int r = 0; r < 4; r++) acc[j][r] = 0.f;

  const short* Aterm[3] = {xb, xb, xr};
  const short* Bterm[3] = {Wp, Wr, Wp};
#pragma unroll
  for (int term = 0; term < 3; ++term) {
    const short* A = Aterm[term] + (size_t)(m0 + fr) * F_ + kg;
    const short* Bt0 = Bterm[term] + (size_t)fr * F_ + kg;
    const short* Bt1 = Bterm[term] + (size_t)(16 + fr) * F_ + kg;
    for (int k0 = 0; k0 < F_; k0 += 32) {
      bf16x8 a = *(const bf16x8*)(A + k0);
      bf16x8 b0 = *(const bf16x8*)(Bt0 + k0);
      bf16x8 b1 = *(const bf16x8*)(Bt1 + k0);
      acc[0] = __builtin_amdgcn_mfma_f32_16x16x32_bf16(a, b0, acc[0], 0, 0, 0);
      acc[1] = __builtin_amdgcn_mfma_f32_16x16x32_bf16(a, b1, acc[1], 0, 0, 0);
    }
  }
  const int cc = lane & 15;
#pragma unroll
  for (int j = 0; j < 2; ++j) {
    const int t = j * 2 + (cc >> 3), e = cc & 7;
#pragma unroll
    for (int r = 0; r < 4; ++r) {
      float s = acc[j][r];
      float mx = s;
      mx = fmaxf(mx, __shfl_xor(mx, 1, 64));
      mx = fmaxf(mx, __shfl_xor(mx, 2, 64));
      mx = fmaxf(mx, __shfl_xor(mx, 4, 64));
      float ex = __expf(s - mx);
      float sm = ex;
      sm += __shfl_xor(sm, 1, 64);
      sm += __shfl_xor(sm, 2, 64);
      sm += __shfl_xor(sm, 4, 64);
      const int b = m0 + (lane >> 4) * 4 + r;
      gates[((size_t)t * B_ + b) * E_ + e] = ex / sm;
    }
  }
}

// ---- 128x128 z-batched GEMM, BK=64, conflict-free swizzled LDS (r7) ----
// + round-8: 2-deep LDS double-buffer with COUNTED vmcnt(8) (T3/T4):
//   iter t: read 16 frags of tile t -> lgkmcnt(0) -> barrier ->
//           stage tile t+2 into buf[t&1] -> 32 MFMA -> vmcnt(8) -> barrier.
// vmcnt(8) leaves the 8 just-issued (t+2) loads in flight and guarantees
// tile t+1 has landed; the drain-0 per K-step is gone.
template <int RELU>
__global__ __launch_bounds__(256, 2) void gemm_bt(const short* __restrict__ A0, size_t sA,
                                                  const short* __restrict__ B0, size_t sB,
                                                  const float* __restrict__ bias0, size_t sBias,
                                                  short* __restrict__ C0, size_t sC,
                                                  int M, int N, int K) {
  const int z = blockIdx.z;
  const short* A = A0 + (size_t)z * sA;
  const short* Bt = B0 + (size_t)z * sB;
  const float* bias = bias0 + (size_t)z * sBias;
  short* C = C0 + (size_t)z * sC;

  __shared__ short As[2][128 * 64];  // 2 x 16 KB
  __shared__ short Bs[2][128 * 64];  // 2 x 16 KB
  const int tid = threadIdx.x;
  const int wid = tid >> 6;
  const int lane = tid & 63;
  const int m0 = blockIdx.x * 128;
  const int n0 = blockIdx.y * 128;
  const int wm = (wid >> 1) * 64;
  const int wn = (wid & 1) * 64;

  f32x4 acc[4][4];
#pragma unroll
  for (int i = 0; i < 4; i++)
#pragma unroll
    for (int j = 0; j < 4; j++)
#pragma unroll
      for (int r = 0; r < 4; r++) acc[i][j][r] = 0.f;

  // ---- staging constants: linear dest, inverse-swizzled global source ----
  const int srow8 = lane >> 3;                       // 0..7
  const int scolb = (((lane & 7) ^ srow8) << 4);     // pre-swizzled source col-byte
  const short* aS = A + (size_t)(m0 + wid * 8 + srow8) * K + (scolb >> 1);
  const short* bS = Bt + (size_t)(n0 + wid * 8 + srow8) * K + (scolb >> 1);

  auto stage = [&](int buf, int k0) {
#pragma unroll
    for (int c = 0; c < 4; ++c) {
      gload16(aS + (size_t)c * 32 * K + k0, (char*)As + buf * 16384 + wid * 1024 + c * 4096);
      gload16(bS + (size_t)c * 32 * K + k0, (char*)Bs + buf * 16384 + wid * 1024 + c * 4096);
    }
  };

  // ---- frag-read constants (swizzle is a pure lane function) ----
  const int fr = lane & 15;
  const int g = lane >> 4;
  const int swzR = (fr & 7) << 4;
  const int rdA = (wm + fr) * 128;     // byte offset within one buffer
  const int rdB = (wn + fr) * 128;
  const int ca0 = (g * 16) ^ swzR;     // ks0 col-byte
  const int ca1 = (64 + g * 16) ^ swzR;// ks1 col-byte

  const int NT = K >> 6;

  // ---- prologue: stage tiles 0 and 1 ----
  stage(0, 0);
  stage(1, (NT > 1 ? 64 : 0));
  asm volatile("s_waitcnt vmcnt(8)" ::: "memory");  // tile 0 landed
  __builtin_amdgcn_sched_barrier(0);
  __builtin_amdgcn_s_barrier();

  for (int t = 0; t < NT; ++t) {
    const int cur = t & 1;
    const char* Ab = (const char*)As + cur * 16384;
    const char* Bb = (const char*)Bs + cur * 16384;
    bf16x8 a0[4], b0[4], a1[4], b1[4];
#pragma unroll
    for (int i = 0; i < 4; i++) {
      a0[i] = *(const bf16x8*)(Ab + rdA + i * 2048 + ca0);
      a1[i] = *(const bf16x8*)(Ab + rdA + i * 2048 + ca1);
      b0[i] = *(const bf16x8*)(Bb + rdB + i * 2048 + ca0);
      b1[i] = *(const bf16x8*)(Bb + rdB + i * 2048 + ca1);
    }
    asm volatile("s_waitcnt lgkmcnt(0)" ::: "memory");  // frags in regs; buf free
    __builtin_amdgcn_sched_barrier(0);
    __builtin_amdgcn_s_barrier();
    __builtin_amdgcn_sched_barrier(0);

    const int k2 = (t + 2 < NT ? t + 2 : NT - 1) * 64;  // clamped tail restage
    stage(cur, k2);  // overwrite the buffer just read

    __builtin_amdgcn_s_setprio(1);
#pragma unroll
    for (int i = 0; i < 4; i++)
#pragma unroll
      for (int j = 0; j < 4; j++)
        acc[i][j] = __builtin_amdgcn_mfma_f32_16x16x32_bf16(a0[i], b0[j], acc[i][j], 0, 0, 0);
#pragma unroll
    for (int i = 0; i < 4; i++)
#pragma unroll
      for (int j = 0; j < 4; j++)
        acc[i][j] = __builtin_amdgcn_mfma_f32_16x16x32_bf16(a1[i], b1[j], acc[i][j], 0, 0, 0);
    __builtin_amdgcn_s_setprio(0);

    asm volatile("s_waitcnt vmcnt(8)" ::: "memory");  // tile t+1 landed; t+2 in flight
    __builtin_amdgcn_sched_barrier(0);
    __builtin_amdgcn_s_barrier();
    __builtin_amdgcn_sched_barrier(0);
  }

  // epilogue: C/D map col=lane&15, row=(lane>>4)*4+reg  [m89-verified]
  const int cr4 = (lane >> 4) * 4;
  const int cc = lane & 15;
#pragma unroll
  for (int j = 0; j < 4; j++) {
    const int col = n0 + wn + j * 16 + cc;
    const float bv = bias[col];
#pragma unroll
    for (int i = 0; i < 4; i++) {
      const int row = m0 + wm + i * 16 + cr4;
#pragma unroll
      for (int r = 0; r < 4; r++) {
        float v = acc[i][j][r] + bv;
        if (RELU) v = fmaxf(v, 0.f);
        C[(size_t)(row + r) * N + col] = f2bf(v);
      }
    }
  }
}

// ---- combine (per chunk): ti[t][lb][u] = sum_e gates[t][b0+lb][e]*EO[e][lb][u] ----
__global__ __launch_bounds__(256) void combine_kernel(const short* __restrict__ EO,
                                                      const float* __restrict__ gates,
                                                      short* __restrict__ ti,
                                                      int Bc, int b0) {
  const int idx = blockIdx.x * 256 + threadIdx.x;  // lb*64 + uc/8
  const int lb = idx >> 6;
  const int uc = (idx & 63) * 8;
  float acc[T_][8];
#pragma unroll
  for (int t = 0; t < T_; t++)
#pragma unroll
    for (int j = 0; j < 8; j++) acc[t][j] = 0.f;
#pragma unroll
  for (int e = 0; e < E_; e++) {
    bf16x8 v = *(const bf16x8*)&EO[((size_t)e * Bc + lb) * U_ + uc];
    float f[8];
#pragma unroll
    for (int j = 0; j < 8; j++) f[j] = bf2f(v[j]);
#pragma unroll
    for (int t = 0; t < T_; t++) {
      const float g = gates[((size_t)t * B_ + b0 + lb) * E_ + e];
#pragma unroll
      for (int j = 0; j < 8; j++) acc[t][j] += g * f[j];
    }
  }
#pragma unroll
  for (int t = 0; t < T_; t++) {
    bf16x8 o;
#pragma unroll
    for (int j = 0; j < 8; j++) o[j] = f2bf(acc[t][j]);
    *(bf16x8*)&ti[((size_t)t * Bc + lb) * U_ + uc] = o;
  }
}

// ---- tower3: out[t*B + b0+lb] = dot(G2[t*Bc+lb], Wt3[t]) + bt3[t] ----
__global__ __launch_bounds__(256) void tower3_kernel(const short* __restrict__ G2,
                                                     const float* __restrict__ Wt3,
                                                     const float* __restrict__ bt3,
                                                     float* __restrict__ out,
                                                     int bcShift, int b0) {
  const int wid = threadIdx.x >> 6, lane = threadIdx.x & 63;
  const int rowl = blockIdx.x * 4 + wid;  // [0, T*Bc)
  const int t = rowl >> bcShift;
  const int lb = rowl & ((1 << bcShift) - 1);
  const short* g = G2 + (size_t)rowl * TH2_;
  s16x4 gv = *(const s16x4*)(g + lane * 4);
  float4 wv = *(const float4*)(Wt3 + t * TH2_ + lane * 4);
  float s = bf2f(gv[0]) * wv.x + bf2f(gv[1]) * wv.y + bf2f(gv[2]) * wv.z + bf2f(gv[3]) * wv.w;
#pragma unroll
  for (int off = 32; off; off >>= 1) s += __shfl_xor(s, off, 64);
  if (lane == 0) out[(size_t)t * B_ + b0 + lb] = s + bt3[t];
}

extern "C" void kernel_launch(void* const* d_in, const int* in_sizes, int n_in,
                              void* d_out, int out_size, void* d_ws, size_t ws_size,
                              hipStream_t stream) {
  const float* x   = (const float*)d_in[0];
  const float* We1 = (const float*)d_in[1];
  const float* be1 = (const float*)d_in[2];
  const float* We2 = (const float*)d_in[3];
  const float* be2 = (const float*)d_in[4];
  const float* We3 = (const float*)d_in[5];
  const float* be3 = (const float*)d_in[6];
  const float* Wg  = (const float*)d_in[7];
  const float* Wt1 = (const float*)d_in[8];
  const float* bt1 = (const float*)d_in[9];
  const float* Wt2 = (const float*)d_in[10];
  const float* bt2 = (const float*)d_in[11];
  const float* Wt3 = (const float*)d_in[12];
  const float* bt3 = (const float*)d_in[13];
  float* out = (float*)d_out;
  (void)in_sizes; (void)n_in; (void)out_size;

  char* ws = (char*)d_ws;
  size_t off = 0;
  auto alloc = [&](size_t bytes) {
    char* p = ws + off;
    off += (bytes + 255) & ~(size_t)255;
    return p;
  };
  // ---- persistent region (~114 MB) ----
  short* We1b  = (short*)alloc((size_t)E_ * F_ * EH1_ * 2);
  short* We2b  = (short*)alloc((size_t)E_ * EH1_ * EH2_ * 2);
  short* We3b  = (short*)alloc((size_t)E_ * EH2_ * U_ * 2);
  short* Wt1b  = (short*)alloc((size_t)T_ * U_ * TH1_ * 2);
  short* Wt2b  = (short*)alloc((size_t)T_ * TH1_ * TH2_ * 2);
  short* Wgp   = (short*)alloc((size_t)32 * F_ * 2);
  short* Wgr   = (short*)alloc((size_t)32 * F_ * 2);
  float* gates = (float*)alloc((size_t)T_ * B_ * E_ * 4);
  short* xb    = (short*)alloc((size_t)B_ * F_ * 2);
  short* xrb   = (short*)alloc((size_t)B_ * F_ * 2);
  const size_t persist = off;

  // ---- chunk sizing: per-row bytes = h1/EO (16384) + h2/{ti,G1,G2} (16384) ----
  int Bc = 16384;
  while (Bc > 256 && persist + (size_t)Bc * 32768 + 65536 > ws_size) Bc >>= 1;
  const int bcShift = __builtin_ctz((unsigned)Bc);

  short* h1 = (short*)alloc((size_t)E_ * Bc * EH1_ * 2);  // also EO overlay
  short* h2 = (short*)alloc((size_t)E_ * Bc * EH2_ * 2);  // also ti/G1/G2 overlay
  short* EO = h1;
  short* ti = h2;                                  // T*Bc*U   = Bc*2048 shorts
  short* G1 = h2 + (size_t)Bc * 2048;              // T*Bc*TH1 = Bc*2048 shorts
  short* G2 = h2 + (size_t)Bc * 4096;              // T*Bc*TH2 = Bc*1024 shorts

  // ---- one-time conversions ----
  conv_dual<<<(B_ * F_ / 8 + 255) / 256, 256, 0, stream>>>(x, xb, xrb, (long)B_ * F_);
  dim3 tb(32, 8);
  trans_conv<<<dim3(F_ / 32, EH1_ / 32, E_), tb, 0, stream>>>(We1, We1b, F_, EH1_);
  trans_conv<<<dim3(EH1_ / 32, EH2_ / 32, E_), tb, 0, stream>>>(We2, We2b, EH1_, EH2_);
  trans_conv<<<dim3(EH2_ / 32, U_ / 32, E_), tb, 0, stream>>>(We3, We3b, EH2_, U_);
  trans_conv<<<dim3(U_ / 32, TH1_ / 32, T_), tb, 0, stream>>>(Wt1, Wt1b, U_, TH1_);
  trans_conv<<<dim3(TH1_ / 32, TH2_ / 32, T_), tb, 0, stream>>>(Wt2, Wt2b, TH1_, TH2_);
  trans_wg<<<(32 * F_) / 256, 256, 0, stream>>>(Wg, Wgp, Wgr);

  // ---- gates: 3-term MFMA + fused softmax ----
  glogits<<<B_ / 64, 256, 0, stream>>>(xb, xrb, Wgp, Wgr, gates);

  // ---- chunked main pipeline (z-batched BK=64 dbuf GEMMs) ----
  for (int b0 = 0; b0 < B_; b0 += Bc) {
    const short* xc = xb + (size_t)b0 * F_;
    gemm_bt<1><<<dim3(Bc / 128, EH1_ / 128, E_), 256, 0, stream>>>(
        xc, 0, We1b, (size_t)F_ * EH1_, be1, EH1_, h1, (size_t)Bc * EH1_, Bc, EH1_, F_);
    gemm_bt<1><<<dim3(Bc / 128, EH2_ / 128, E_), 256, 0, stream>>>(
        h1, (size_t)Bc * EH1_, We2b, (size_t)EH1_ * EH2_, be2, EH2_, h2, (size_t)Bc * EH2_,
        Bc, EH2_, EH1_);
    gemm_bt<0><<<dim3(Bc / 128, U_ / 128, E_), 256, 0, stream>>>(
        h2, (size_t)Bc * EH2_, We3b, (size_t)EH2_ * U_, be3, U_, EO, (size_t)Bc * U_,
        Bc, U_, EH2_);
    combine_kernel<<<(Bc * 64) / 256, 256, 0, stream>>>(EO, gates, ti, Bc, b0);
    gemm_bt<1><<<dim3(Bc / 128, TH1_ / 128, T_), 256, 0, stream>>>(
        ti, (size_t)Bc * U_, Wt1b, (size_t)U_ * TH1_, bt1, TH1_, G1, (size_t)Bc * TH1_,
        Bc, TH1_, U_);
    gemm_bt<1><<<dim3(Bc / 128, TH2_ / 128, T_), 256, 0, stream>>>(
        G1, (size_t)Bc * TH1_, Wt2b, (size_t)TH1_ * TH2_, bt2, TH2_, G2, (size_t)Bc * TH2_,
        Bc, TH2_, TH1_);
    tower3_kernel<<<T_ * Bc / 4, 256, 0, stream>>>(G2, Wt3, bt3, out, bcShift, b0);
  }
}